// Round 15
// baseline (76.444 us; speedup 1.0000x reference)
//
#include <hip/hip_runtime.h>

#define BB 2
#define NN 1000
#define NC 81
#define CC 80
#define SCORE_THRESH 0.05f
#define NMS_THRESH 0.5f
#define DET_PER_IMG 100
#define K1_BLOCKS 125   // 125 * 16 rows = 2000 = B*N exactly

// K1 (verified R14): softmax stats + transposed score write + output zeroing.
__global__ __launch_bounds__(256) void softmax_zero_kernel(
    const float* __restrict__ logits,   // [B*N, 81]
    float* __restrict__ sc,             // [B*C, N]
    float* __restrict__ out) {          // [B*C, N, 5] — zeroed here
    __shared__ __align__(16) float stage[16 * NC];   // 5184 B
    __shared__ float s_mx[16], s_inv[16];
    const int tid = threadIdx.x;
    const int blk = blockIdx.x;

    // zero the whole output, coalesced grid-stride (200000 float4 / 32000 thr)
    float4* outv = (float4*)out;
    for (int k = blk * 256 + tid; k < BB * CC * NN * 5 / 4; k += K1_BLOCKS * 256)
        outv[k] = make_float4(0.f, 0.f, 0.f, 0.f);

    // coalesced stage of this block's 16 rows (offset blk*5184 B, 16B-mult)
    const int r0 = blk * 16;
    const float4* src = (const float4*)(logits + (size_t)r0 * NC);
    float4* dst = (float4*)stage;
    for (int k = tid; k < 16 * NC / 4; k += 256) dst[k] = src[k];
    __syncthreads();

    // per-row stats, sequential numeric path (absmax-0.0 anchor, 8 runs)
    if (tid < 16) {
        const float* z = stage + tid * NC;
        float mx = z[0];
        #pragma unroll
        for (int k = 1; k < NC; k++) mx = fmaxf(mx, z[k]);
        float sum = 0.f;
        #pragma unroll
        for (int k = 0; k < NC; k++) sum += expf(z[k] - mx);
        s_mx[tid] = mx;
        s_inv[tid] = 1.f / sum;
    }
    __syncthreads();

    // transposed write: idx -> (c = idx/16, i = idx%16); 16 consecutive n per c
    for (int idx = tid; idx < CC * 16; idx += 256) {
        int c = idx >> 4, i = idx & 15;
        int r = r0 + i;
        int b = r / NN, n = r - b * NN;
        sc[((size_t)(b * CC + c)) * NN + n] =
            expf(stage[i * NC + c + 1] - s_mx[i]) * s_inv[i];
    }
}

// K2: one block per (image, class) task. R15: when V<=64, sort/decode/NMS/
// scatter all run in wave 0 (same-wave LDS ops are in-order -> no barriers),
// and NMS is bitmask-based: parallel overlap-column precompute (pipelined)
// + a ~25cyc/iter serial mask loop, replacing ~200cyc/iter LDS-latency chain.
__global__ __launch_bounds__(256) void nms_task_kernel(
    const float* __restrict__ sc,      // [B*C, N]
    const float* __restrict__ boxreg,  // [B*N, C*4]
    const float* __restrict__ props,   // [B*N, 4]
    float* __restrict__ out) {         // [B*C, N, 5] — pre-zeroed by K1
    __shared__ float s_vs[NN];
    __shared__ int   s_vn[NN];
    __shared__ int   s_sn[NN];
    __shared__ float s_ss[NN];
    __shared__ float s_x1[NN], s_y1[NN], s_x2[NN], s_y2[NN], s_ar[NN];
    __shared__ int   s_supp[NN];
    __shared__ int   s_kf[NN];
    __shared__ int   s_V;

    const int t = blockIdx.x;
    const int b = t / CC, c = t % CC;
    const int tid = threadIdx.x;
    const int rowbase = b * NN;

    if (tid == 0) s_V = 0;
    __syncthreads();

    // compact straight from registers: thread tid<250 owns scores 4tid..4tid+3
    if (tid < NN / 4) {
        float4 v = ((const float4*)(sc + (size_t)t * NN))[tid];
        float e[4] = {v.x, v.y, v.z, v.w};
        #pragma unroll
        for (int j = 0; j < 4; j++) {
            if (e[j] > SCORE_THRESH) {
                int i = atomicAdd(&s_V, 1);
                s_vn[i] = tid * 4 + j;
                s_vs[i] = e[j];
            }
        }
    }
    __syncthreads();
    const int V = s_V;

    if (V <= 64) {
        // ---------------- wave-0 fast path: no further barriers ------------
        if (tid < 64) {
            const int lane = tid;
            const bool act = lane < V;

            // sort: rank among valid (stable: score desc, index asc) — all
            // participating lanes are in wave 0, LDS ops stay in-order.
            if (act) {
                float si = s_vs[lane];
                int   ni = s_vn[lane];
                int p = 0;
                for (int u = 0; u < V; u++) {
                    float su = s_vs[u];
                    p += (su > si || (su == si && s_vn[u] < ni)) ? 1 : 0;
                }
                s_sn[p] = ni;
                s_ss[p] = si;
            }
            __builtin_amdgcn_wave_barrier();   // compiler fence (no-op instr)

            // decode item `lane` (boxes live in registers; LDS copy only for
            // the broadcast reads in the overlap precompute)
            float x1j = 0.f, y1j = 0.f, x2j = 0.f, y2j = 0.f, aj = 0.f, scj = 0.f;
            if (act) {
                int n = s_sn[lane];
                scj = s_ss[lane];
                int row = rowbase + n;
                float p0 = props[row * 4 + 0], p1 = props[row * 4 + 1];
                float p2 = props[row * 4 + 2], p3 = props[row * 4 + 3];
                float px = (p0 + p2) * 0.5f, py = (p1 + p3) * 0.5f;
                float pw = p2 - p0, ph = p3 - p1;
                const float* rg = boxreg + (size_t)row * (CC * 4) + c * 4;
                float gx = rg[0] * pw + px;
                float gy = rg[1] * ph + py;
                float gw = pw * expf(rg[2]);
                float gh = ph * expf(rg[3]);
                x1j = gx - gw * 0.5f; y1j = gy - gh * 0.5f;
                x2j = gx + gw * 0.5f; y2j = gy + gh * 0.5f;
                aj = (x2j - x1j) * (y2j - y1j);
                s_x1[lane] = x1j; s_y1[lane] = y1j;
                s_x2[lane] = x2j; s_y2[lane] = y2j; s_ar[lane] = aj;
            }
            __builtin_amdgcn_wave_barrier();

            // overlap-column precompute: dependency-free, LDS reads pipeline.
            // bit i of ov = (IoU(i, lane) > thresh); identical operand order
            // to the verified loop -> bit-identical decisions.
            unsigned long long ov = 0ull;
            for (int i = 0; i < V; ++i) {
                float x1i = s_x1[i], y1i = s_y1[i];
                float x2i = s_x2[i], y2i = s_y2[i], ai = s_ar[i];
                float xx = fmaxf(x1i, x1j);
                float yy = fmaxf(y1i, y1j);
                float w = fmaxf(fminf(x2i, x2j) - xx, 0.f);
                float h = fmaxf(fminf(y2i, y2j) - yy, 0.f);
                float inter = w * h;
                float iou = inter / (ai + aj - inter);
                if (act && iou > NMS_THRESH) ov |= (1ull << i);
            }

            // serial greedy loop: pure mask ops + ballot (~25 cyc/iter)
            unsigned long long suppm = 0ull;
            int mykf = 0, kc = 0;
            for (int i = 0; i < V; ++i) {
                if ((suppm >> i) & 1ull) continue;
                ++kc;
                if (lane == i) mykf = kc;
                bool sup = act && (lane > i) && ((ov >> i) & 1ull);
                suppm |= __ballot(sup);
            }

            // scatter straight from registers (cap applies to output only)
            if (act && mykf > 0 && mykf <= DET_PER_IMG) {
                size_t o = ((size_t)t * NN + (size_t)lane) * 5;
                out[o + 0] = x1j;
                out[o + 1] = y1j;
                out[o + 2] = x2j;
                out[o + 3] = y2j;
                out[o + 4] = scj;
            }
        }
    } else {
        // ---------------- multi-wave fallback (verified R9 body) -----------
        for (int i = tid; i < V; i += 256) {
            float si = s_vs[i];
            int   ni = s_vn[i];
            int p = 0;
            for (int u = 0; u < V; u++) {
                float su = s_vs[u];
                p += (su > si || (su == si && s_vn[u] < ni)) ? 1 : 0;
            }
            s_sn[p] = ni;
            s_ss[p] = si;
        }
        __syncthreads();

        for (int p = tid; p < V; p += 256) {
            int n = s_sn[p];
            int row = rowbase + n;
            float p0 = props[row * 4 + 0], p1 = props[row * 4 + 1];
            float p2 = props[row * 4 + 2], p3 = props[row * 4 + 3];
            float px = (p0 + p2) * 0.5f, py = (p1 + p3) * 0.5f;
            float pw = p2 - p0, ph = p3 - p1;
            const float* rg = boxreg + (size_t)row * (CC * 4) + c * 4;
            float gx = rg[0] * pw + px;
            float gy = rg[1] * ph + py;
            float gw = pw * expf(rg[2]);
            float gh = ph * expf(rg[3]);
            float x1 = gx - gw * 0.5f, y1 = gy - gh * 0.5f;
            float x2 = gx + gw * 0.5f, y2 = gy + gh * 0.5f;
            s_x1[p] = x1; s_y1[p] = y1; s_x2[p] = x2; s_y2[p] = y2;
            s_ar[p] = (x2 - x1) * (y2 - y1);
            s_supp[p] = 0;
            s_kf[p] = 0;
        }
        __syncthreads();

        int kc = 0;
        for (int i = 0; i < V; i++) {
            if (s_supp[i]) continue;   // uniform pre-barrier LDS read
            kc++;
            if (tid == 0) s_kf[i] = kc;
            float x1i = s_x1[i], y1i = s_y1[i], x2i = s_x2[i], y2i = s_y2[i];
            float ai = s_ar[i];
            for (int j = i + 1 + tid; j < V; j += 256) {
                float xx = fmaxf(x1i, s_x1[j]);
                float yy = fmaxf(y1i, s_y1[j]);
                float w = fmaxf(fminf(x2i, s_x2[j]) - xx, 0.f);
                float h = fmaxf(fminf(y2i, s_y2[j]) - yy, 0.f);
                float inter = w * h;
                float iou = inter / (ai + s_ar[j] - inter);
                if (iou > NMS_THRESH) s_supp[j] = 1;
            }
            __syncthreads();
        }
        __syncthreads();

        for (int p = tid; p < V; p += 256) {
            int kf = s_kf[p];
            if (kf > 0 && kf <= DET_PER_IMG) {
                size_t o = ((size_t)t * NN + (size_t)p) * 5;
                out[o + 0] = s_x1[p];
                out[o + 1] = s_y1[p];
                out[o + 2] = s_x2[p];
                out[o + 3] = s_y2[p];
                out[o + 4] = s_ss[p];
            }
        }
    }
}

extern "C" void kernel_launch(void* const* d_in, const int* in_sizes, int n_in,
                              void* d_out, int out_size, void* d_ws, size_t ws_size,
                              hipStream_t stream) {
    const float* logits = (const float*)d_in[0];   // [B*N, 81]
    const float* boxreg = (const float*)d_in[1];   // [B*N, C*4]
    const float* props  = (const float*)d_in[2];   // [B, N, 4]
    float* out = (float*)d_out;                    // [B, C, N, 5]
    float* sc  = (float*)d_ws;                     // [B*C, N] scores (640 KB)

    softmax_zero_kernel<<<K1_BLOCKS, 256, 0, stream>>>(logits, sc, out);
    nms_task_kernel<<<BB * CC, 256, 0, stream>>>(sc, boxreg, props, out);
}